// Round 12
// baseline (245.521 us; speedup 1.0000x reference)
//
#include <hip/hip_runtime.h>

#define N_NODESC 20000
#define N_EDGESC 1280000
#define NB 256          // csr-build blocks
#define EPB 5000        // edges per build block
#define REGC 2560000    // bytes per 64-ch chunk region (20000 * 128B)

typedef short bf16x8 __attribute__((ext_vector_type(8)));
typedef float f32x4 __attribute__((ext_vector_type(4)));

// ---- workspace layout (bytes, 128-aligned) ----
constexpr size_t OFF_DEG      = 0;          // int[20000]
constexpr size_t OFF_ROWSTART = 81920;      // int[20001]
constexpr size_t OFF_INVDEG   = 163840;     // float[20000]
constexpr size_t OFF_BSUM     = 245760;     // int[128]
constexpr size_t OFF_S1       = 246272;     // float[20000]
constexpr size_t OFF_T1       = 326272;     // float[20000]
constexpr size_t OFF_PART     = 406272;     // float[5120]
constexpr size_t OFF_HIST     = 426752;     // ushort[256][20000] = 10.24 MB
constexpr size_t OFF_CSR      = 10666752;   // ushort[1280000] (+128B overread pad)
constexpr size_t OFF_XC       = 13226880;   // bf16 chunk-major [4][20000][64ch] = 10.24 MB
constexpr size_t OFF_MEANC    = 23466880;   // bf16 chunk-major [4][20000][64ch] = 10.24 MB
constexpr size_t OFF_W1LB     = 33706880;   // bf16[256][256] row-major
constexpr size_t OFF_W1RB     = 33837952;   // bf16[256][256] (end ~34 MB)

static __device__ __forceinline__ unsigned f2bf(float f) {
    unsigned u = __float_as_uint(f);
    return ((u + 0x7fffu + ((u >> 16) & 1u)) >> 16) & 0xffffu;  // RTNE
}
static __device__ __forceinline__ float bflo(unsigned w) {
    return __uint_as_float(w << 16);
}
static __device__ __forceinline__ float bfhi(unsigned w) {
    return __uint_as_float(w & 0xffff0000u);
}

// merged: blocks [0,2564) cast x->chunk-major bf16 + W1 -> bf16 (+ zero s1/t1/bsum);
// blocks [2564,2820) build per-block LDS histogram of dst
__global__ void __launch_bounds__(256) k_prep(
        const float4* __restrict__ x, const float4* __restrict__ w1l,
        const float4* __restrict__ w1r, char* __restrict__ xc,
        uint4* __restrict__ w1lb, uint4* __restrict__ w1rb,
        float* __restrict__ s1, float* __restrict__ t1,
        int* __restrict__ bsum, const int* __restrict__ ei,
        unsigned short* __restrict__ hist) {
    __shared__ unsigned int lh[10000];
    int b = blockIdx.x, t = threadIdx.x;
    if (b < 2564) {
        int g = b * 256 + t;    // 8-float group id
        if (g < N_NODESC) { s1[g] = 0.0f; t1[g] = 0.0f; }
        if (g < 128) bsum[g] = 0;
        float4 a, c;
        uint4 o;
        if (g < 640000) {
            a = x[g * 2]; c = x[g * 2 + 1];
            o.x = f2bf(a.x) | (f2bf(a.y) << 16);
            o.y = f2bf(a.z) | (f2bf(a.w) << 16);
            o.z = f2bf(c.x) | (f2bf(c.y) << 16);
            o.w = f2bf(c.z) | (f2bf(c.w) << 16);
            int n = g >> 5, cb = g & 31;
            int chunk = cb >> 3, piece = cb & 7;   // 64-ch chunk, 16B piece
            *(uint4*)(xc + (size_t)chunk * REGC + (size_t)n * 128 + piece * 16) = o;
            return;
        }
        const float4* src; uint4* dst; int off;
        if (g < 648192) { src = w1l; dst = w1lb; off = g - 640000; }
        else            { src = w1r; dst = w1rb; off = g - 648192; }
        a = src[off * 2]; c = src[off * 2 + 1];
        o.x = f2bf(a.x) | (f2bf(a.y) << 16);
        o.y = f2bf(a.z) | (f2bf(a.w) << 16);
        o.z = f2bf(c.x) | (f2bf(c.y) << 16);
        o.w = f2bf(c.z) | (f2bf(c.w) << 16);
        dst[off] = o;
        return;
    }
    int hb = b - 2564;
    for (int w = t; w < 10000; w += 256) lh[w] = 0;
    __syncthreads();
    int base = hb * EPB;
    for (int i = t; i < EPB; i += 256) {
        int d = ei[N_EDGESC + base + i];
        atomicAdd(&lh[d >> 1], (d & 1) ? 0x10000u : 1u);
    }
    __syncthreads();
    unsigned int* gh = (unsigned int*)(hist + (size_t)hb * N_NODESC);
    for (int w = t; w < 10000; w += 256) gh[w] = lh[w];
}

// per bin: exclusive prefix across 256 build blocks (values cached in VGPRs);
// deg[bin] total; fused block-sum into bsum via atomics
__global__ void __launch_bounds__(256) k_prefix(unsigned short* __restrict__ hist,
                                                int* __restrict__ deg,
                                                int* __restrict__ bsum) {
    __shared__ int wtot[4][64];
    int t = threadIdx.x;
    int lb = t & 63, sub = t >> 6;
    int bin = blockIdx.x * 64 + lb;
    bool ok = bin < N_NODESC;
    int vals[64];
    int run = 0;
    if (ok) {
        #pragma unroll
        for (int i = 0; i < 64; i++) {
            vals[i] = hist[(size_t)(sub * 64 + i) * N_NODESC + bin];
            run += vals[i];
        }
    }
    wtot[sub][lb] = run;
    __syncthreads();
    int off = 0, total = 0;
    for (int w = 0; w < 4; w++) {
        int v = wtot[w][lb];
        if (w < sub) off += v;
        total += v;
    }
    if (sub == 0) {
        int tv = ok ? total : 0;
        if (ok) deg[bin] = total;
        #pragma unroll
        for (int o2 = 32; o2 > 0; o2 >>= 1) tv += __shfl_down(tv, o2);
        if (lb == 0) atomicAdd(&bsum[(blockIdx.x * 64) >> 8], tv);
    }
    if (ok) {
        int run2 = off;
        #pragma unroll
        for (int i = 0; i < 64; i++) {
            hist[(size_t)(sub * 64 + i) * N_NODESC + bin] = (unsigned short)run2;
            run2 += vals[i];
        }
    }
}

// scan of deg -> row_start, inv_deg; block offset from local prefix of bsum[0..78]
__global__ void __launch_bounds__(256) k_scan(
        const int* __restrict__ deg, const int* __restrict__ bsum,
        int* __restrict__ row_start, float* __restrict__ inv_deg) {
    __shared__ int wsum[4];
    int i = blockIdx.x * 256 + threadIdx.x;
    int lane = threadIdx.x & 63, wid = threadIdx.x >> 6;
    int boff = 0;
    for (int b = 0; b < (int)blockIdx.x; b++) boff += bsum[b];
    int v = (i < N_NODESC) ? deg[i] : 0;
    int incl = v;
    #pragma unroll
    for (int off = 1; off < 64; off <<= 1) {
        int n = __shfl_up(incl, off);
        if (lane >= off) incl += n;
    }
    if (lane == 63) wsum[wid] = incl;
    __syncthreads();
    int wpre = 0;
    #pragma unroll
    for (int w = 0; w < 4; w++) wpre += (w < wid) ? wsum[w] : 0;
    if (i < N_NODESC) {
        row_start[i] = boff + wpre + incl - v;
        inv_deg[i]   = 1.0f / (float)max(v, 1);
    }
    if (i == 0) row_start[N_NODESC] = N_EDGESC;
}

// scatter edges into CSR (ushort src ids): rank via LDS atomics + hist prefix
__global__ void __launch_bounds__(256) k_fill2(const int* __restrict__ ei,
        const int* __restrict__ row_start, const unsigned short* __restrict__ hist,
        unsigned short* __restrict__ csr) {
    __shared__ unsigned int lh[10000];
    int b = blockIdx.x, t = threadIdx.x;
    for (int w = t; w < 10000; w += 256) lh[w] = 0;
    __syncthreads();
    int base = b * EPB;
    const unsigned short* hb = hist + (size_t)b * N_NODESC;
    for (int i = t; i < EPB; i += 256) {
        int e = base + i;
        int d = ei[N_EDGESC + e];
        int s = ei[e];
        unsigned int old = atomicAdd(&lh[d >> 1], (d & 1) ? 0x10000u : 1u);
        int rank = (d & 1) ? (int)(old >> 16) : (int)(old & 0xffffu);
        int pos = row_start[d] + (int)hb[d] + rank;
        csr[pos] = (unsigned short)s;
    }
}

// wave = (node, 64-ch chunk); chunk = blkIdx&3 (2.56MB/XCD, ~98% L2 hit —
// r9/r10/r11 measured). 2B/lane: lane owns one channel (no unpack beyond
// lshl16, no reduce, no predication). Edge src via READLANE -> SGPR, so the
// gather compiles to saddr-form global_load_ushort with a single
// v_lshl_add_u32 voffset per edge (r8-measured SGPR-addressing economy),
// instead of r11's bpermute + v_mov + 64-bit VALU address adds.
__global__ void __launch_bounds__(256) k_agg(const char* __restrict__ xc,
        const int* __restrict__ row_start, const unsigned short* __restrict__ csr,
        const float* __restrict__ inv_deg, char* __restrict__ meanc) {
    int wid = threadIdx.x >> 6, lane = threadIdx.x & 63;
    int chunk = blockIdx.x & 3;
    int node = (blockIdx.x >> 2) * 4 + wid;
    const unsigned short* xbase =
        (const unsigned short*)(xc + (size_t)chunk * REGC);
    int lane2 = lane;                  // element index within 64-ch row
    int start = row_start[node], end = row_start[node + 1];
    float a0 = 0.f, a1 = 0.f, a2 = 0.f, a3 = 0.f;
    float a4 = 0.f, a5 = 0.f, a6 = 0.f, a7 = 0.f;
    for (int j = start; j < end; j += 64) {
        int cnt = min(64, end - j);
        int idx = (int)csr[j + lane];       // <=126B overread ok (padded)
        int k = 0;
        for (; k + 8 <= cnt; k += 8) {
            int s0 = __builtin_amdgcn_readlane(idx, k);
            int s1 = __builtin_amdgcn_readlane(idx, k + 1);
            int s2 = __builtin_amdgcn_readlane(idx, k + 2);
            int s3 = __builtin_amdgcn_readlane(idx, k + 3);
            int s4 = __builtin_amdgcn_readlane(idx, k + 4);
            int s5 = __builtin_amdgcn_readlane(idx, k + 5);
            int s6 = __builtin_amdgcn_readlane(idx, k + 6);
            int s7 = __builtin_amdgcn_readlane(idx, k + 7);
            unsigned v0 = xbase[s0 * 64 + lane2];
            unsigned v1 = xbase[s1 * 64 + lane2];
            unsigned v2 = xbase[s2 * 64 + lane2];
            unsigned v3 = xbase[s3 * 64 + lane2];
            unsigned v4 = xbase[s4 * 64 + lane2];
            unsigned v5 = xbase[s5 * 64 + lane2];
            unsigned v6 = xbase[s6 * 64 + lane2];
            unsigned v7 = xbase[s7 * 64 + lane2];
            a0 += __uint_as_float(v0 << 16);
            a1 += __uint_as_float(v1 << 16);
            a2 += __uint_as_float(v2 << 16);
            a3 += __uint_as_float(v3 << 16);
            a4 += __uint_as_float(v4 << 16);
            a5 += __uint_as_float(v5 << 16);
            a6 += __uint_as_float(v6 << 16);
            a7 += __uint_as_float(v7 << 16);
        }
        for (; k < cnt; k++) {
            int s0 = __builtin_amdgcn_readlane(idx, k);
            a0 += __uint_as_float((unsigned)xbase[s0 * 64 + lane2] << 16);
        }
    }
    float acc = ((a0 + a1) + (a2 + a3)) + ((a4 + a5) + (a6 + a7));
    float inv = inv_deg[node];
    *(unsigned short*)(meanc + (size_t)chunk * REGC + (size_t)node * 128 +
                       lane * 2) = (unsigned short)f2bf(acc * inv);
}

// h1 = relu([mean|x] @ [W1l|W1r]^T + b1) via bf16 MFMA; A from chunk-major,
// fused epilogue s1 += h1.w2l, t1 += h1.w2r. 64x128 tile (A re-read 2x not 4x).
__global__ void __launch_bounds__(256) k_gemm(const char* __restrict__ meanc,
        const char* __restrict__ xc, const uint4* __restrict__ w1lb4,
        const uint4* __restrict__ w1rb4, const float* __restrict__ b1,
        const float* __restrict__ w2l, const float* __restrict__ w2r,
        float* __restrict__ s1, float* __restrict__ t1) {
    __shared__ __align__(16) unsigned short As[64][72];
    __shared__ __align__(16) unsigned short Bs[128][72];
    int t = threadIdx.x;
    int m0 = blockIdx.x * 64, n0 = blockIdx.y * 128;
    int wv = t >> 6, l = t & 63, lr = l & 15, quad = l >> 4;
    f32x4 acc[8] = {};
    for (int kt = 0; kt < 8; kt++) {
        const char* Achar = (kt < 4) ? meanc : xc;
        const uint4* Bsrc = (kt < 4) ? w1lb4 : w1rb4;
        int chunk = kt & 3;
        int k0q = chunk * 8;           // uint4 offset of the 64-ch window in a W row
        #pragma unroll
        for (int p = 0; p < 2; p++) {  // A: 64 rows x 128B
            int f = t + p * 256;
            int row = f >> 3, c16 = f & 7;
            int m = m0 + row;
            uint4 va = (m < N_NODESC)
                ? *(const uint4*)(Achar + (size_t)chunk * REGC + (size_t)m * 128 +
                                  c16 * 16)
                : make_uint4(0, 0, 0, 0);
            *(uint4*)&As[row][c16 * 8] = va;
        }
        #pragma unroll
        for (int p = 0; p < 4; p++) {  // B: 128 rows x 128B
            int f = t + p * 256;
            int row = f >> 3, c16 = f & 7;
            uint4 vb = Bsrc[(size_t)(n0 + row) * 32 + k0q + c16];
            *(uint4*)&Bs[row][c16 * 8] = vb;
        }
        __syncthreads();
        #pragma unroll
        for (int ks = 0; ks < 64; ks += 32) {
            bf16x8 af = *(const bf16x8*)&As[wv * 16 + lr][ks + quad * 8];
            #pragma unroll
            for (int jj = 0; jj < 8; jj++) {
                bf16x8 bf = *(const bf16x8*)&Bs[jj * 16 + lr][ks + quad * 8];
                acc[jj] = __builtin_amdgcn_mfma_f32_16x16x32_bf16(
                              af, bf, acc[jj], 0, 0, 0);
            }
        }
        __syncthreads();
    }
    float ps[4] = {0, 0, 0, 0}, pt[4] = {0, 0, 0, 0};
    #pragma unroll
    for (int jj = 0; jj < 8; jj++) {
        int col = n0 + jj * 16 + lr;
        float bb = b1[col], wl = w2l[col], wr = w2r[col];
        #pragma unroll
        for (int r = 0; r < 4; r++) {
            float h = fmaxf(acc[jj][r] + bb, 0.0f);
            ps[r] += h * wl; pt[r] += h * wr;
        }
    }
    #pragma unroll
    for (int r = 0; r < 4; r++) {
        #pragma unroll
        for (int off = 8; off > 0; off >>= 1) {
            ps[r] += __shfl_down(ps[r], off, 16);
            pt[r] += __shfl_down(pt[r], off, 16);
        }
    }
    if (lr == 0) {
        int mb = m0 + wv * 16 + quad * 4;
        #pragma unroll
        for (int r = 0; r < 4; r++) {
            int m = mb + r;
            if (m < N_NODESC) {
                atomicAdd(&s1[m], ps[r]);
                atomicAdd(&t1[m], pt[r]);
            }
        }
    }
}

// layer-2 scalar aggregation + epilogue + fc dot; plain-store block partials
__global__ void __launch_bounds__(256) k_layer2(
        const int* __restrict__ row_start, const unsigned short* __restrict__ csr,
        const float* __restrict__ inv_deg, const float* __restrict__ s1,
        const float* __restrict__ t1, const float* __restrict__ b2,
        const float* __restrict__ fc_w, float* __restrict__ part) {
    __shared__ float pw[4];
    int wid = threadIdx.x >> 6, lane = threadIdx.x & 63;
    int node = blockIdx.x * 4 + wid;
    float contrib = 0.0f;
    if (node < N_NODESC) {
        int start = row_start[node], end = row_start[node + 1];
        float s = 0.0f;
        for (int j = start + lane; j < end; j += 64) s += s1[csr[j]];
        #pragma unroll
        for (int off = 32; off > 0; off >>= 1) s += __shfl_down(s, off);
        if (lane == 0) {
            float h2 = fmaxf(s * inv_deg[node] + b2[0] + t1[node], 0.0f);
            contrib = h2 * fc_w[node];
        }
    }
    if (lane == 0) pw[wid] = contrib;
    __syncthreads();
    if (threadIdx.x == 0)
        part[blockIdx.x] = pw[0] + pw[1] + pw[2] + pw[3];
}

__global__ void __launch_bounds__(256) k_final(const float* __restrict__ part,
        const float* __restrict__ fc_b, float* __restrict__ out) {
    __shared__ float sm[4];
    int t = threadIdx.x;
    float s = 0.0f;
    for (int i = t; i < 5000; i += 256) s += part[i];
    #pragma unroll
    for (int off = 32; off > 0; off >>= 1) s += __shfl_down(s, off);
    if ((t & 63) == 0) sm[t >> 6] = s;
    __syncthreads();
    if (t == 0) out[0] = sm[0] + sm[1] + sm[2] + sm[3] + fc_b[0];
}

extern "C" void kernel_launch(void* const* d_in, const int* in_sizes, int n_in,
                              void* d_out, int out_size, void* d_ws, size_t ws_size,
                              hipStream_t stream) {
    const float* x    = (const float*)d_in[0];
    const int*   ei   = (const int*)d_in[1];
    const float* w1l  = (const float*)d_in[2];
    const float* b1   = (const float*)d_in[3];
    const float* w1r  = (const float*)d_in[4];
    const float* w2l  = (const float*)d_in[5];
    const float* b2   = (const float*)d_in[6];
    const float* w2r  = (const float*)d_in[7];
    const float* fcw  = (const float*)d_in[8];
    const float* fcb  = (const float*)d_in[9];
    float* out = (float*)d_out;

    char* ws = (char*)d_ws;
    int*    deg       = (int*)(ws + OFF_DEG);
    int*    row_start = (int*)(ws + OFF_ROWSTART);
    float*  inv_deg   = (float*)(ws + OFF_INVDEG);
    int*    bsum      = (int*)(ws + OFF_BSUM);
    float*  s1        = (float*)(ws + OFF_S1);
    float*  t1        = (float*)(ws + OFF_T1);
    float*  part      = (float*)(ws + OFF_PART);
    unsigned short* hist = (unsigned short*)(ws + OFF_HIST);
    unsigned short* csr  = (unsigned short*)(ws + OFF_CSR);
    char*   xc        = ws + OFF_XC;
    char*   meanc     = ws + OFF_MEANC;
    uint4*  w1lb4     = (uint4*)(ws + OFF_W1LB);
    uint4*  w1rb4     = (uint4*)(ws + OFF_W1RB);

    k_prep<<<2820, 256, 0, stream>>>((const float4*)x, (const float4*)w1l,
                                     (const float4*)w1r, xc, w1lb4, w1rb4,
                                     s1, t1, bsum, ei, hist);
    k_prefix<<<313, 256, 0, stream>>>(hist, deg, bsum);
    k_scan<<<79, 256, 0, stream>>>(deg, bsum, row_start, inv_deg);
    k_fill2<<<NB, 256, 0, stream>>>(ei, row_start, hist, csr);
    k_agg<<<20000, 256, 0, stream>>>(xc, row_start, csr, inv_deg, meanc);
    dim3 ggrid(313, 2);
    k_gemm<<<ggrid, 256, 0, stream>>>(meanc, xc, w1lb4, w1rb4,
                                      b1, w2l, w2r, s1, t1);
    k_layer2<<<5000, 256, 0, stream>>>(row_start, csr, inv_deg, s1, t1, b2,
                                       fcw, part);
    k_final<<<1, 256, 0, stream>>>(part, fcb, out);
}

// Round 13
// 233.042 us; speedup vs baseline: 1.0535x; 1.0535x over previous
//
#include <hip/hip_runtime.h>

#define N_NODESC 20000
#define N_EDGESC 1280000
#define NB 256          // csr-build blocks
#define EPB 5000        // edges per build block
#define REGC 2560000    // bytes per 64-ch chunk region (20000 * 128B)

typedef short bf16x8 __attribute__((ext_vector_type(8)));
typedef float f32x4 __attribute__((ext_vector_type(4)));

// ---- workspace layout (bytes, 128-aligned) ----
constexpr size_t OFF_DEG      = 0;          // int[20000]
constexpr size_t OFF_ROWSTART = 81920;      // int[20001]
constexpr size_t OFF_INVDEG   = 163840;     // float[20000]
constexpr size_t OFF_BSUM     = 245760;     // int[128]
constexpr size_t OFF_S1       = 246272;     // float[20000]
constexpr size_t OFF_T1       = 326272;     // float[20000]
constexpr size_t OFF_PART     = 406272;     // float[5120]
constexpr size_t OFF_HIST     = 426752;     // ushort[256][20000] = 10.24 MB
constexpr size_t OFF_CSR      = 10666752;   // ushort[1280000] (+128B overread pad)
constexpr size_t OFF_XC       = 13226880;   // bf16 chunk-major [4][20000][64ch] = 10.24 MB
constexpr size_t OFF_MEANC    = 23466880;   // bf16 chunk-major [4][20000][64ch] = 10.24 MB
constexpr size_t OFF_W1LB     = 33706880;   // bf16[256][256] row-major
constexpr size_t OFF_W1RB     = 33837952;   // bf16[256][256] (end ~34 MB)

static __device__ __forceinline__ unsigned f2bf(float f) {
    unsigned u = __float_as_uint(f);
    return ((u + 0x7fffu + ((u >> 16) & 1u)) >> 16) & 0xffffu;  // RTNE
}
static __device__ __forceinline__ float bflo(unsigned w) {
    return __uint_as_float(w << 16);
}
static __device__ __forceinline__ float bfhi(unsigned w) {
    return __uint_as_float(w & 0xffff0000u);
}

// merged: blocks [0,2564) cast x->chunk-major bf16 + W1 -> bf16 (+ zero s1/t1/bsum);
// blocks [2564,2820) build per-block LDS histogram of dst
__global__ void __launch_bounds__(256) k_prep(
        const float4* __restrict__ x, const float4* __restrict__ w1l,
        const float4* __restrict__ w1r, char* __restrict__ xc,
        uint4* __restrict__ w1lb, uint4* __restrict__ w1rb,
        float* __restrict__ s1, float* __restrict__ t1,
        int* __restrict__ bsum, const int* __restrict__ ei,
        unsigned short* __restrict__ hist) {
    __shared__ unsigned int lh[10000];
    int b = blockIdx.x, t = threadIdx.x;
    if (b < 2564) {
        int g = b * 256 + t;    // 8-float group id
        if (g < N_NODESC) { s1[g] = 0.0f; t1[g] = 0.0f; }
        if (g < 128) bsum[g] = 0;
        float4 a, c;
        uint4 o;
        if (g < 640000) {
            a = x[g * 2]; c = x[g * 2 + 1];
            o.x = f2bf(a.x) | (f2bf(a.y) << 16);
            o.y = f2bf(a.z) | (f2bf(a.w) << 16);
            o.z = f2bf(c.x) | (f2bf(c.y) << 16);
            o.w = f2bf(c.z) | (f2bf(c.w) << 16);
            int n = g >> 5, cb = g & 31;
            int chunk = cb >> 3, piece = cb & 7;   // 64-ch chunk, 16B piece
            *(uint4*)(xc + (size_t)chunk * REGC + (size_t)n * 128 + piece * 16) = o;
            return;
        }
        const float4* src; uint4* dst; int off;
        if (g < 648192) { src = w1l; dst = w1lb; off = g - 640000; }
        else            { src = w1r; dst = w1rb; off = g - 648192; }
        a = src[off * 2]; c = src[off * 2 + 1];
        o.x = f2bf(a.x) | (f2bf(a.y) << 16);
        o.y = f2bf(a.z) | (f2bf(a.w) << 16);
        o.z = f2bf(c.x) | (f2bf(c.y) << 16);
        o.w = f2bf(c.z) | (f2bf(c.w) << 16);
        dst[off] = o;
        return;
    }
    int hb = b - 2564;
    for (int w = t; w < 10000; w += 256) lh[w] = 0;
    __syncthreads();
    int base = hb * EPB;
    for (int i = t; i < EPB; i += 256) {
        int d = ei[N_EDGESC + base + i];
        atomicAdd(&lh[d >> 1], (d & 1) ? 0x10000u : 1u);
    }
    __syncthreads();
    unsigned int* gh = (unsigned int*)(hist + (size_t)hb * N_NODESC);
    for (int w = t; w < 10000; w += 256) gh[w] = lh[w];
}

// per bin: exclusive prefix across 256 build blocks (values cached in VGPRs);
// deg[bin] total; fused block-sum into bsum via atomics
__global__ void __launch_bounds__(256) k_prefix(unsigned short* __restrict__ hist,
                                                int* __restrict__ deg,
                                                int* __restrict__ bsum) {
    __shared__ int wtot[4][64];
    int t = threadIdx.x;
    int lb = t & 63, sub = t >> 6;
    int bin = blockIdx.x * 64 + lb;
    bool ok = bin < N_NODESC;
    int vals[64];
    int run = 0;
    if (ok) {
        #pragma unroll
        for (int i = 0; i < 64; i++) {
            vals[i] = hist[(size_t)(sub * 64 + i) * N_NODESC + bin];
            run += vals[i];
        }
    }
    wtot[sub][lb] = run;
    __syncthreads();
    int off = 0, total = 0;
    for (int w = 0; w < 4; w++) {
        int v = wtot[w][lb];
        if (w < sub) off += v;
        total += v;
    }
    if (sub == 0) {
        int tv = ok ? total : 0;
        if (ok) deg[bin] = total;
        #pragma unroll
        for (int o2 = 32; o2 > 0; o2 >>= 1) tv += __shfl_down(tv, o2);
        if (lb == 0) atomicAdd(&bsum[(blockIdx.x * 64) >> 8], tv);
    }
    if (ok) {
        int run2 = off;
        #pragma unroll
        for (int i = 0; i < 64; i++) {
            hist[(size_t)(sub * 64 + i) * N_NODESC + bin] = (unsigned short)run2;
            run2 += vals[i];
        }
    }
}

// scan of deg -> row_start, inv_deg; block offset from local prefix of bsum[0..78]
__global__ void __launch_bounds__(256) k_scan(
        const int* __restrict__ deg, const int* __restrict__ bsum,
        int* __restrict__ row_start, float* __restrict__ inv_deg) {
    __shared__ int wsum[4];
    int i = blockIdx.x * 256 + threadIdx.x;
    int lane = threadIdx.x & 63, wid = threadIdx.x >> 6;
    int boff = 0;
    for (int b = 0; b < (int)blockIdx.x; b++) boff += bsum[b];
    int v = (i < N_NODESC) ? deg[i] : 0;
    int incl = v;
    #pragma unroll
    for (int off = 1; off < 64; off <<= 1) {
        int n = __shfl_up(incl, off);
        if (lane >= off) incl += n;
    }
    if (lane == 63) wsum[wid] = incl;
    __syncthreads();
    int wpre = 0;
    #pragma unroll
    for (int w = 0; w < 4; w++) wpre += (w < wid) ? wsum[w] : 0;
    if (i < N_NODESC) {
        row_start[i] = boff + wpre + incl - v;
        inv_deg[i]   = 1.0f / (float)max(v, 1);
    }
    if (i == 0) row_start[N_NODESC] = N_EDGESC;
}

// scatter edges into CSR (ushort src ids): rank via LDS atomics + hist prefix
__global__ void __launch_bounds__(256) k_fill2(const int* __restrict__ ei,
        const int* __restrict__ row_start, const unsigned short* __restrict__ hist,
        unsigned short* __restrict__ csr) {
    __shared__ unsigned int lh[10000];
    int b = blockIdx.x, t = threadIdx.x;
    for (int w = t; w < 10000; w += 256) lh[w] = 0;
    __syncthreads();
    int base = b * EPB;
    const unsigned short* hb = hist + (size_t)b * N_NODESC;
    for (int i = t; i < EPB; i += 256) {
        int e = base + i;
        int d = ei[N_EDGESC + e];
        int s = ei[e];
        unsigned int old = atomicAdd(&lh[d >> 1], (d & 1) ? 0x10000u : 1u);
        int rank = (d & 1) ? (int)(old >> 16) : (int)(old & 0xffffu);
        int pos = row_start[d] + (int)hb[d] + rank;
        csr[pos] = (unsigned short)s;
    }
}

// wave = (node, 64-ch chunk); chunk = blkIdx&3 (2.56MB/XCD, ~98% L2 hit).
// 2B/lane: lane owns one channel. KEY FIX (r12 post-mortem): address the
// gather as wave-uniform 64-bit base + 32-bit VGPR voffset computed with int
// shifts ((s<<7)+(lane<<1), max 2.56M < 2^31) so the compiler emits
// saddr-form global_load_ushort + one v_lshl_add_u32 — not the per-edge
// 64-bit mad/addc chain that (size_t) indexing generated (15 inst/edge-chunk
// measured r12; target 5).
__global__ void __launch_bounds__(256) k_agg(const char* __restrict__ xc,
        const int* __restrict__ row_start, const unsigned short* __restrict__ csr,
        const float* __restrict__ inv_deg, char* __restrict__ meanc) {
    int wid = threadIdx.x >> 6, lane = threadIdx.x & 63;
    int chunk = blockIdx.x & 3;
    int node = (blockIdx.x >> 2) * 4 + wid;
    const char* xbase = xc + (size_t)chunk * REGC;
    unsigned loff = (unsigned)(lane << 1);     // byte offset of lane's channel
    int start = row_start[node], end = row_start[node + 1];
    float a0 = 0.f, a1 = 0.f, a2 = 0.f, a3 = 0.f;
    float a4 = 0.f, a5 = 0.f, a6 = 0.f, a7 = 0.f;
    for (int j = start; j < end; j += 64) {
        int cnt = min(64, end - j);
        int idx = (int)csr[j + lane];       // <=126B overread ok (padded)
        int k = 0;
        for (; k + 8 <= cnt; k += 8) {
            unsigned o0 = ((unsigned)__builtin_amdgcn_readlane(idx, k)     << 7) + loff;
            unsigned o1 = ((unsigned)__builtin_amdgcn_readlane(idx, k + 1) << 7) + loff;
            unsigned o2 = ((unsigned)__builtin_amdgcn_readlane(idx, k + 2) << 7) + loff;
            unsigned o3 = ((unsigned)__builtin_amdgcn_readlane(idx, k + 3) << 7) + loff;
            unsigned o4 = ((unsigned)__builtin_amdgcn_readlane(idx, k + 4) << 7) + loff;
            unsigned o5 = ((unsigned)__builtin_amdgcn_readlane(idx, k + 5) << 7) + loff;
            unsigned o6 = ((unsigned)__builtin_amdgcn_readlane(idx, k + 6) << 7) + loff;
            unsigned o7 = ((unsigned)__builtin_amdgcn_readlane(idx, k + 7) << 7) + loff;
            unsigned v0 = *(const unsigned short*)(xbase + o0);
            unsigned v1 = *(const unsigned short*)(xbase + o1);
            unsigned v2 = *(const unsigned short*)(xbase + o2);
            unsigned v3 = *(const unsigned short*)(xbase + o3);
            unsigned v4 = *(const unsigned short*)(xbase + o4);
            unsigned v5 = *(const unsigned short*)(xbase + o5);
            unsigned v6 = *(const unsigned short*)(xbase + o6);
            unsigned v7 = *(const unsigned short*)(xbase + o7);
            a0 += __uint_as_float(v0 << 16);
            a1 += __uint_as_float(v1 << 16);
            a2 += __uint_as_float(v2 << 16);
            a3 += __uint_as_float(v3 << 16);
            a4 += __uint_as_float(v4 << 16);
            a5 += __uint_as_float(v5 << 16);
            a6 += __uint_as_float(v6 << 16);
            a7 += __uint_as_float(v7 << 16);
        }
        for (; k < cnt; k++) {
            unsigned o0 = ((unsigned)__builtin_amdgcn_readlane(idx, k) << 7) + loff;
            a0 += __uint_as_float((unsigned)*(const unsigned short*)(xbase + o0) << 16);
        }
    }
    float acc = ((a0 + a1) + (a2 + a3)) + ((a4 + a5) + (a6 + a7));
    float inv = inv_deg[node];
    *(unsigned short*)(meanc + (size_t)chunk * REGC + (size_t)node * 128 +
                       lane * 2) = (unsigned short)f2bf(acc * inv);
}

// h1 = relu([mean|x] @ [W1l|W1r]^T + b1) via bf16 MFMA; A from chunk-major,
// fused epilogue s1 += h1.w2l, t1 += h1.w2r. 64x128 tile (A re-read 2x not 4x).
__global__ void __launch_bounds__(256) k_gemm(const char* __restrict__ meanc,
        const char* __restrict__ xc, const uint4* __restrict__ w1lb4,
        const uint4* __restrict__ w1rb4, const float* __restrict__ b1,
        const float* __restrict__ w2l, const float* __restrict__ w2r,
        float* __restrict__ s1, float* __restrict__ t1) {
    __shared__ __align__(16) unsigned short As[64][72];
    __shared__ __align__(16) unsigned short Bs[128][72];
    int t = threadIdx.x;
    int m0 = blockIdx.x * 64, n0 = blockIdx.y * 128;
    int wv = t >> 6, l = t & 63, lr = l & 15, quad = l >> 4;
    f32x4 acc[8] = {};
    for (int kt = 0; kt < 8; kt++) {
        const char* Achar = (kt < 4) ? meanc : xc;
        const uint4* Bsrc = (kt < 4) ? w1lb4 : w1rb4;
        int chunk = kt & 3;
        int k0q = chunk * 8;           // uint4 offset of the 64-ch window in a W row
        #pragma unroll
        for (int p = 0; p < 2; p++) {  // A: 64 rows x 128B
            int f = t + p * 256;
            int row = f >> 3, c16 = f & 7;
            int m = m0 + row;
            uint4 va = (m < N_NODESC)
                ? *(const uint4*)(Achar + (size_t)chunk * REGC + (size_t)m * 128 +
                                  c16 * 16)
                : make_uint4(0, 0, 0, 0);
            *(uint4*)&As[row][c16 * 8] = va;
        }
        #pragma unroll
        for (int p = 0; p < 4; p++) {  // B: 128 rows x 128B
            int f = t + p * 256;
            int row = f >> 3, c16 = f & 7;
            uint4 vb = Bsrc[(size_t)(n0 + row) * 32 + k0q + c16];
            *(uint4*)&Bs[row][c16 * 8] = vb;
        }
        __syncthreads();
        #pragma unroll
        for (int ks = 0; ks < 64; ks += 32) {
            bf16x8 af = *(const bf16x8*)&As[wv * 16 + lr][ks + quad * 8];
            #pragma unroll
            for (int jj = 0; jj < 8; jj++) {
                bf16x8 bf = *(const bf16x8*)&Bs[jj * 16 + lr][ks + quad * 8];
                acc[jj] = __builtin_amdgcn_mfma_f32_16x16x32_bf16(
                              af, bf, acc[jj], 0, 0, 0);
            }
        }
        __syncthreads();
    }
    float ps[4] = {0, 0, 0, 0}, pt[4] = {0, 0, 0, 0};
    #pragma unroll
    for (int jj = 0; jj < 8; jj++) {
        int col = n0 + jj * 16 + lr;
        float bb = b1[col], wl = w2l[col], wr = w2r[col];
        #pragma unroll
        for (int r = 0; r < 4; r++) {
            float h = fmaxf(acc[jj][r] + bb, 0.0f);
            ps[r] += h * wl; pt[r] += h * wr;
        }
    }
    #pragma unroll
    for (int r = 0; r < 4; r++) {
        #pragma unroll
        for (int off = 8; off > 0; off >>= 1) {
            ps[r] += __shfl_down(ps[r], off, 16);
            pt[r] += __shfl_down(pt[r], off, 16);
        }
    }
    if (lr == 0) {
        int mb = m0 + wv * 16 + quad * 4;
        #pragma unroll
        for (int r = 0; r < 4; r++) {
            int m = mb + r;
            if (m < N_NODESC) {
                atomicAdd(&s1[m], ps[r]);
                atomicAdd(&t1[m], pt[r]);
            }
        }
    }
}

// layer-2 scalar aggregation + epilogue + fc dot; plain-store block partials
__global__ void __launch_bounds__(256) k_layer2(
        const int* __restrict__ row_start, const unsigned short* __restrict__ csr,
        const float* __restrict__ inv_deg, const float* __restrict__ s1,
        const float* __restrict__ t1, const float* __restrict__ b2,
        const float* __restrict__ fc_w, float* __restrict__ part) {
    __shared__ float pw[4];
    int wid = threadIdx.x >> 6, lane = threadIdx.x & 63;
    int node = blockIdx.x * 4 + wid;
    float contrib = 0.0f;
    if (node < N_NODESC) {
        int start = row_start[node], end = row_start[node + 1];
        float s = 0.0f;
        for (int j = start + lane; j < end; j += 64) s += s1[csr[j]];
        #pragma unroll
        for (int off = 32; off > 0; off >>= 1) s += __shfl_down(s, off);
        if (lane == 0) {
            float h2 = fmaxf(s * inv_deg[node] + b2[0] + t1[node], 0.0f);
            contrib = h2 * fc_w[node];
        }
    }
    if (lane == 0) pw[wid] = contrib;
    __syncthreads();
    if (threadIdx.x == 0)
        part[blockIdx.x] = pw[0] + pw[1] + pw[2] + pw[3];
}

__global__ void __launch_bounds__(256) k_final(const float* __restrict__ part,
        const float* __restrict__ fc_b, float* __restrict__ out) {
    __shared__ float sm[4];
    int t = threadIdx.x;
    float s = 0.0f;
    for (int i = t; i < 5000; i += 256) s += part[i];
    #pragma unroll
    for (int off = 32; off > 0; off >>= 1) s += __shfl_down(s, off);
    if ((t & 63) == 0) sm[t >> 6] = s;
    __syncthreads();
    if (t == 0) out[0] = sm[0] + sm[1] + sm[2] + sm[3] + fc_b[0];
}

extern "C" void kernel_launch(void* const* d_in, const int* in_sizes, int n_in,
                              void* d_out, int out_size, void* d_ws, size_t ws_size,
                              hipStream_t stream) {
    const float* x    = (const float*)d_in[0];
    const int*   ei   = (const int*)d_in[1];
    const float* w1l  = (const float*)d_in[2];
    const float* b1   = (const float*)d_in[3];
    const float* w1r  = (const float*)d_in[4];
    const float* w2l  = (const float*)d_in[5];
    const float* b2   = (const float*)d_in[6];
    const float* w2r  = (const float*)d_in[7];
    const float* fcw  = (const float*)d_in[8];
    const float* fcb  = (const float*)d_in[9];
    float* out = (float*)d_out;

    char* ws = (char*)d_ws;
    int*    deg       = (int*)(ws + OFF_DEG);
    int*    row_start = (int*)(ws + OFF_ROWSTART);
    float*  inv_deg   = (float*)(ws + OFF_INVDEG);
    int*    bsum      = (int*)(ws + OFF_BSUM);
    float*  s1        = (float*)(ws + OFF_S1);
    float*  t1        = (float*)(ws + OFF_T1);
    float*  part      = (float*)(ws + OFF_PART);
    unsigned short* hist = (unsigned short*)(ws + OFF_HIST);
    unsigned short* csr  = (unsigned short*)(ws + OFF_CSR);
    char*   xc        = ws + OFF_XC;
    char*   meanc     = ws + OFF_MEANC;
    uint4*  w1lb4     = (uint4*)(ws + OFF_W1LB);
    uint4*  w1rb4     = (uint4*)(ws + OFF_W1RB);

    k_prep<<<2820, 256, 0, stream>>>((const float4*)x, (const float4*)w1l,
                                     (const float4*)w1r, xc, w1lb4, w1rb4,
                                     s1, t1, bsum, ei, hist);
    k_prefix<<<313, 256, 0, stream>>>(hist, deg, bsum);
    k_scan<<<79, 256, 0, stream>>>(deg, bsum, row_start, inv_deg);
    k_fill2<<<NB, 256, 0, stream>>>(ei, row_start, hist, csr);
    k_agg<<<20000, 256, 0, stream>>>(xc, row_start, csr, inv_deg, meanc);
    dim3 ggrid(313, 2);
    k_gemm<<<ggrid, 256, 0, stream>>>(meanc, xc, w1lb4, w1rb4,
                                      b1, w2l, w2r, s1, t1);
    k_layer2<<<5000, 256, 0, stream>>>(row_start, csr, inv_deg, s1, t1, b2,
                                       fcw, part);
    k_final<<<1, 256, 0, stream>>>(part, fcb, out);
}